// Round 20
// baseline (295.556 us; speedup 1.0000x reference)
//
#include <hip/hip_runtime.h>
#include <hip/hip_bf16.h>

typedef __attribute__((ext_vector_type(8))) short short8;
typedef __attribute__((ext_vector_type(4))) float floatx4;
typedef unsigned short u16;

#define D 256
#define BM 64
#define NT 256
#define NBLK 512

__device__ __forceinline__ short f2bf(float f) {
    return __builtin_bit_cast(short, __float2bfloat16(f));
}

// prep: blocks [0,256): W1 fp32 [k][n] -> W1F bf16 MFMA-fragment-major:
// W1F[((k0t*16+nt)*64+lane)*8+j] = W1[k0t*32+(lane>>4)*8+j][nt*16+(lane&15)]
//       blocks [256,384): zero d_out.
__global__ void prep_kernel(const float* __restrict__ W1, u16* __restrict__ W1F,
                            float* __restrict__ out, int outn) {
    const int b = blockIdx.x;
    if (b < D) {
        const int k = b, n = threadIdx.x;
        const int k0t = k >> 5, g = (k >> 3) & 3, j = k & 7;
        const int nt = n >> 4, l15 = n & 15;
        W1F[(long)((((k0t << 4) + nt) << 6) + (g << 4) + l15) * 8 + j] = (u16)f2bf(W1[k * D + n]);
    } else {
        int i = (b - D) * 256 + threadIdx.x;
        const int stride = (gridDim.x - D) * 256;
        for (; i < outn; i += stride) out[i] = 0.f;
    }
}

struct R8 { floatx4 f0, f1; };

// Persistent head, B-in-registers: grid 512 = 2 blocks/CU, 4 waves, 33 KiB LDS.
// __launch_bounds__(256,2) -> 2 waves/SIMD -> 256-VGPR budget: each wave holds
// its 64-col B-quarter (bfr[32], 128 VGPR) across all ~24 tiles. Compute phase
// is pure ds_read+MFMA (ZERO vmem) -> no L2-latency chains (R19's diagnosed
// limiter), block lifetime shrinks, 2 staggered blocks/CU raise HBM duty.
__launch_bounds__(NT, 2)
__global__ void head_kernel(const float* __restrict__ forces,
                            const float* __restrict__ V_st,
                            const u16*   __restrict__ W1F,
                            const float* __restrict__ b1,
                            const float* __restrict__ W2,
                            const float* __restrict__ b2,
                            const int*   __restrict__ idx_t,
                            float* __restrict__ out,
                            int E) {
    // A frag f = k0t*4 + (row>>4); in-frag slot ((g<<4)|(row&15))*8 + j shorts
    __shared__ u16 Albs[32 * 512];    // 32 KiB
    __shared__ float s_red[4][BM];    // 1 KiB

    const int tid  = threadIdx.x;
    const int lane = tid & 63;
    const int wq   = tid >> 6;        // 0..3: col quarter owned by this wave
    const int l15  = lane & 15;
    const int g    = lane >> 4;       // 0..3
    const int ntiles = E / BM;        // 12500

    // ---- prologue: hoist this wave's B-quarter into registers (once) ----
    short8 bfr[32];
#pragma unroll
    for (int k0t = 0; k0t < 8; ++k0t)
#pragma unroll
        for (int nc = 0; nc < 4; ++nc)
            bfr[k0t * 4 + nc] =
                *(const short8*)(W1F + (long)((k0t * 16 + wq * 4 + nc) * 64 + lane) * 8);

    float b1v[4], w2v[4];
#pragma unroll
    for (int nc = 0; nc < 4; ++nc) {
        int n = wq * 64 + nc * 16 + l15;
        b1v[nc] = b1[n];
        w2v[nc] = W2[n];
    }
    const float b2v = b2[0];

    const int arow = tid >> 2;        // 0..63
    const int agg  = tid & 3;
    const int aslot = ((agg << 4) | (arow & 15)) * 8;
    const int art   = arow >> 4;

    for (long t = blockIdx.x; t < (long)ntiles; t += NBLK) {
        const long row0 = t * BM;

        // ---- scatter-operand prefetch: wave wq owns rows [wq*16, wq*16+16) ----
        float vx = 0.f, vy = 0.f, vz = 0.f;
        int nd = -1;
        if (lane < 16) {
            long e = row0 + wq * 16 + lane;
            vx = V_st[e * 3 + 0]; vy = V_st[e * 3 + 1]; vz = V_st[e * 3 + 2];
            nd = idx_t[e];
        }

        // ---- stage A: burst 16 loads -> cvt -> fragment-major LDS ----
        const float* abase = forces + (row0 + arow) * (long)D + agg * 8;
        R8 r[8];
#pragma unroll
        for (int k0t = 0; k0t < 8; ++k0t) {
            r[k0t].f0 = *(const floatx4*)(abase + k0t * 32);
            r[k0t].f1 = *(const floatx4*)(abase + k0t * 32 + 4);
        }
#pragma unroll
        for (int k0t = 0; k0t < 8; ++k0t) {
            short8 a;
#pragma unroll
            for (int j = 0; j < 4; ++j) { a[j] = f2bf(r[k0t].f0[j]); a[4 + j] = f2bf(r[k0t].f1[j]); }
            *(short8*)&Albs[(k0t * 4 + art) * 512 + aslot] = a;
        }
        __syncthreads();   // A ready (drain coincides with needed wait)

        // ---- MFMA: 64 rows x 64 cols; ZERO vmem in this phase ----
        floatx4 acc[4][4];
#pragma unroll
        for (int rt = 0; rt < 4; ++rt)
#pragma unroll
            for (int nc = 0; nc < 4; ++nc)
                acc[rt][nc] = (floatx4){0.f, 0.f, 0.f, 0.f};

#pragma unroll
        for (int k0t = 0; k0t < 8; ++k0t) {
            short8 af[4];
#pragma unroll
            for (int rt = 0; rt < 4; ++rt)
                af[rt] = *(const short8*)&Albs[(k0t * 4 + rt) * 512 + lane * 8];
#pragma unroll
            for (int rt = 0; rt < 4; ++rt)
#pragma unroll
                for (int nc = 0; nc < 4; ++nc)
                    acc[rt][nc] = __builtin_amdgcn_mfma_f32_16x16x32_bf16(
                        af[rt], bfr[k0t * 4 + nc], acc[rt][nc], 0, 0, 0);
        }

        // ---- epilogue: silu(z+b1) dot W2 over this wave's 64 cols ----
        float part[4][4];
#pragma unroll
        for (int rt = 0; rt < 4; ++rt)
#pragma unroll
            for (int rr = 0; rr < 4; ++rr) {
                float sv = 0.f;
#pragma unroll
                for (int nc = 0; nc < 4; ++nc) {
                    float z = acc[rt][nc][rr] + b1v[nc];
                    float h = z / (1.f + __expf(-z));
                    sv += h * w2v[nc];
                }
                part[rt][rr] = sv;
            }

#pragma unroll
        for (int off = 1; off < 16; off <<= 1)
#pragma unroll
            for (int rt = 0; rt < 4; ++rt)
#pragma unroll
                for (int rr = 0; rr < 4; ++rr)
                    part[rt][rr] += __shfl_xor(part[rt][rr], off, 16);

        if (l15 == 0) {
#pragma unroll
            for (int rt = 0; rt < 4; ++rt)
#pragma unroll
                for (int rr = 0; rr < 4; ++rr)
                    s_red[wq][rt * 16 + g * 4 + rr] = part[rt][rr];
        }
        __syncthreads();   // s_red ready

        // ---- scatter: wave wq scatters its 16 rows (operands in regs) ----
        if (nd >= 0) {
            int row = wq * 16 + lane;
            float sv = s_red[0][row] + s_red[1][row] + s_red[2][row] + s_red[3][row] + b2v;
            atomicAdd(&out[(long)nd * 3 + 0], sv * vx);
            atomicAdd(&out[(long)nd * 3 + 1], sv * vy);
            atomicAdd(&out[(long)nd * 3 + 2], sv * vz);
        }
        // next tile's stage barrier separates these s_red reads from rewrites
    }
}

extern "C" void kernel_launch(void* const* d_in, const int* in_sizes, int n_in,
                              void* d_out, int out_size, void* d_ws, size_t ws_size,
                              hipStream_t stream) {
    const float* forces = (const float*)d_in[0];
    const float* V_st   = (const float*)d_in[1];
    const float* W1     = (const float*)d_in[2];
    const float* b1     = (const float*)d_in[3];
    const float* W2     = (const float*)d_in[4];
    const float* b2     = (const float*)d_in[5];
    const int*   idx    = (const int*)d_in[6];
    const int E = in_sizes[6];

    u16* W1F = (u16*)d_ws;  // 256*256*2 = 131072 B

    prep_kernel<<<D + 128, 256, 0, stream>>>(W1, W1F, (float*)d_out, out_size);
    head_kernel<<<NBLK, NT, 0, stream>>>(forces, V_st, W1F, b1, W2, b2, idx,
                                         (float*)d_out, E);
}